// Round 1
// baseline (230.451 us; speedup 1.0000x reference)
//
#include <hip/hip_runtime.h>

#define DD 6
#define FF 64
#define NS 30       // 2*D*RANK + D
#define TSTRIDE 32  // padded table row stride (floats) for aligned float4 gathers

// Phase 1: per node/edge, mean over D rows then project by W-half (+b for nodes).
// One wave per unit; lane = feature for the mean, lane = output j for the dot.
__global__ __launch_bounds__(256) void precompute_kernel(
    const float* __restrict__ x, const float* __restrict__ e,
    const float* __restrict__ W, const float* __restrict__ b,
    float* __restrict__ xW, float* __restrict__ eW, int N, int E)
{
    int gw   = (blockIdx.x * 256 + threadIdx.x) >> 6;  // wave-uniform
    int lane = threadIdx.x & 63;
    int total = N + E;
    if (gw >= total) return;
    bool isNode = gw < N;
    int u = isNode ? gw : (gw - N);
    const float* src = (isNode ? x : e) + (size_t)u * (DD * FF);

    float acc = 0.f;
    #pragma unroll
    for (int d = 0; d < DD; ++d) acc += src[d * FF + lane];
    acc *= (1.0f / 6.0f);   // xm[u][lane]

    const float* Wp = W + (isNode ? 0 : FF * NS);
    int j = (lane < NS) ? lane : 0;
    float o = 0.f;
    #pragma unroll
    for (int f = 0; f < FF; ++f) {
        float v = __shfl(acc, f, 64);          // readlane broadcast
        o = fmaf(v, Wp[f * NS + j], o);        // W is 15KB -> L1 resident
    }
    if (lane < NS) {
        if (isNode) o += b[lane];
        (isNode ? xW : eW)[(size_t)u * TSTRIDE + lane] = o;
    }
}

// Phase 2: per NNZ, s = sigmoid(xW[row]+eW[col]); maps = A B^T + diag(C).
// 256 nnz/block; maps staged in LDS (stride 37 = conflict-free) then
// block-linear float4 copy to the attrs region.
__global__ __launch_bounds__(256) void sheaf_kernel(
    const int* __restrict__ rows, const int* __restrict__ cols,
    const float* __restrict__ xW, const float* __restrict__ eW,
    float* __restrict__ out_attr, int nnz)
{
    __shared__ float mlds[256 * 37];
    int tid  = threadIdx.x;
    int base = blockIdx.x * 256;
    int k    = base + tid;
    if (k < nnz) {
        int r = rows[k];
        int c = cols[k];
        const float4* xp = (const float4*)(xW + (size_t)r * TSTRIDE);
        const float4* ep = (const float4*)(eW + (size_t)c * TSTRIDE);
        float s[32];
        #pragma unroll
        for (int q = 0; q < 8; ++q) {
            float4 a = xp[q], bb = ep[q];
            s[q*4+0] = a.x + bb.x; s[q*4+1] = a.y + bb.y;
            s[q*4+2] = a.z + bb.z; s[q*4+3] = a.w + bb.w;
        }
        #pragma unroll
        for (int jj = 0; jj < NS; ++jj) s[jj] = 1.0f / (1.0f + __expf(-s[jj]));

        float* ml = mlds + tid * 37;
        #pragma unroll
        for (int i = 0; i < DD; ++i) {
            float a0 = s[i*2], a1 = s[i*2+1];
            #pragma unroll
            for (int jj = 0; jj < DD; ++jj) {
                float v = fmaf(a0, s[12 + jj*2], a1 * s[12 + jj*2 + 1]);
                if (i == jj) v += s[24 + i];
                ml[i*6 + jj] = v;
            }
        }
    }
    __syncthreads();
    int cnt = nnz - base; if (cnt > 256) cnt = 256;
    int tot = cnt * 36;                      // always divisible by 4
    float* gp = out_attr + (size_t)base * 36;
    for (int g = tid * 4; g < tot; g += 1024) {
        float v[4];
        #pragma unroll
        for (int i = 0; i < 4; ++i) {
            int gg = g + i;
            int l  = gg / 36;
            int m  = gg - l * 36;
            v[i] = mlds[l * 37 + m];
        }
        *(float4*)(gp + g) = make_float4(v[0], v[1], v[2], v[3]);
    }
}

// Phase 3: index outputs. idx0[g] = 6*row[g/36] + (g%36)/6 ; idx1[g] = 6*col[g/36] + (g%36)%6
__global__ __launch_bounds__(256) void idx_kernel(
    const int* __restrict__ rows, const int* __restrict__ cols,
    float* __restrict__ out_idx0, float* __restrict__ out_idx1, int tot)
{
    int g = (blockIdx.x * 256 + threadIdx.x) * 4;
    if (g >= tot) return;
    float v0[4], v1[4];
    #pragma unroll
    for (int i = 0; i < 4; ++i) {
        int gg = g + i;
        int l  = gg / 36;
        int m  = gg - l * 36;
        int m6 = m / 6;
        int r  = rows[l];
        int c  = cols[l];
        v0[i] = (float)(6 * r + m6);
        v1[i] = (float)(6 * c + (m - m6 * 6));
    }
    *(float4*)(out_idx0 + g) = make_float4(v0[0], v0[1], v0[2], v0[3]);
    *(float4*)(out_idx1 + g) = make_float4(v1[0], v1[1], v1[2], v1[3]);
}

extern "C" void kernel_launch(void* const* d_in, const int* in_sizes, int n_in,
                              void* d_out, int out_size, void* d_ws, size_t ws_size,
                              hipStream_t stream)
{
    const float* x = (const float*)d_in[0];
    const float* e = (const float*)d_in[1];
    const float* W = (const float*)d_in[2];
    const float* b = (const float*)d_in[3];
    const int* hidx = (const int*)d_in[4];

    int N   = in_sizes[0] / (DD * FF);
    int E   = in_sizes[1] / (DD * FF);
    int nnz = in_sizes[4] / 2;
    const int* rows = hidx;
    const int* cols = hidx + nnz;

    float* out = (float*)d_out;
    size_t M = (size_t)nnz * 36;
    float* out_idx0 = out;
    float* out_idx1 = out + M;
    float* out_attr = out + 2 * M;

    // Tables: prefer d_ws; fall back to staging inside the idx0 region, which
    // is only overwritten by idx_kernel AFTER sheaf_kernel has consumed them
    // (stream-ordered), and sheaf_kernel writes only the disjoint attrs region.
    size_t tableBytes = ((size_t)N + (size_t)E) * TSTRIDE * sizeof(float);
    float* xW = (ws_size >= tableBytes) ? (float*)d_ws : out_idx0;
    float* eW = xW + (size_t)N * TSTRIDE;

    int totalUnits = N + E;                       // one wave each
    int pcBlocks = (totalUnits + 3) / 4;          // 4 waves per 256-thread block
    precompute_kernel<<<pcBlocks, 256, 0, stream>>>(x, e, W, b, xW, eW, N, E);

    int sBlocks = (nnz + 255) / 256;
    sheaf_kernel<<<sBlocks, 256, 0, stream>>>(rows, cols, xW, eW, out_attr, nnz);

    int tot = nnz * 36;
    int iBlocks = (tot / 4 + 255) / 256;
    idx_kernel<<<iBlocks, 256, 0, stream>>>(rows, cols, out_idx0, out_idx1, tot);
}